// Round 1
// baseline (668.500 us; speedup 1.0000x reference)
//
#include <hip/hip_runtime.h>
#include <math.h>

#define Bc 32
#define Sc 2048
#define Dc 1024
#define Mc 1024
#define DMc 2048
#define NCH 32
#define LNEPS 1e-5f

__device__ __forceinline__ float block_reduce_sum(float v, float* sm) {
    for (int o = 32; o; o >>= 1) v += __shfl_xor(v, o);
    int wid = threadIdx.x >> 6;
    if ((threadIdx.x & 63) == 0) sm[wid] = v;
    __syncthreads();
    float r = sm[0] + sm[1] + sm[2] + sm[3];
    __syncthreads();
    return r;
}

// wv_row[d] = sum_m Wv[d,m]; block Dc handles bvsum = sum(bv)
__global__ void k_prep(const float* __restrict__ Wv, const float* __restrict__ bv,
                       float* __restrict__ wv_row, float* __restrict__ bvsum) {
    __shared__ float sm[4];
    int d = blockIdx.x;
    const float* src = (d < Dc) ? (Wv + (size_t)d * Mc) : bv;
    float v = 0.f;
    for (int m = threadIdx.x; m < Mc; m += 256) v += src[m];
    v = block_reduce_sum(v, sm);
    if (threadIdx.x == 0) { if (d < Dc) wv_row[d] = v; else *bvsum = v; }
}

// C[b,n] = sum_k A[b,k]*W[k*1024+n]  (N fixed = 1024)
// mode 0: C = acc + bias[n]
// mode 1: C = scale*(acc + bias[n]*rs[b])
// grid (16, 4), block 256
template <int K>
__global__ void k_gemm_nt(const float* __restrict__ A, const float* __restrict__ W,
                          const float* __restrict__ bias, float* __restrict__ C,
                          int mode, const float* __restrict__ rs, float scale) {
    constexpr int KSH = (K == 1024) ? 10 : 11;
    __shared__ float Als[8 * K];
    int n0 = blockIdx.x * 64;
    int b0 = blockIdx.y * 8;
    for (int i = threadIdx.x; i < 8 * K; i += 256) {
        int r = i >> KSH, c = i & (K - 1);
        Als[r * K + c] = A[(size_t)(b0 + r) * K + c];
    }
    __syncthreads();
    int n = n0 + (threadIdx.x & 63);
    int bl = threadIdx.x >> 6;
    float acc0 = 0.f, acc1 = 0.f;
    const float* a0 = Als + bl * K;
    const float* a1 = Als + (bl + 4) * K;
#pragma unroll 8
    for (int k = 0; k < K; ++k) {
        float wv = W[(size_t)k * 1024 + n];
        acc0 = fmaf(a0[k], wv, acc0);
        acc1 = fmaf(a1[k], wv, acc1);
    }
    float bn = bias[n];
    int bi0 = b0 + bl, bi1 = b0 + bl + 4;
    if (mode == 0) {
        C[(size_t)bi0 * 1024 + n] = acc0 + bn;
        C[(size_t)bi1 * 1024 + n] = acc1 + bn;
    } else {
        C[(size_t)bi0 * 1024 + n] = scale * (acc0 + bn * rs[bi0]);
        C[(size_t)bi1 * 1024 + n] = scale * (acc1 + bn * rs[bi1]);
    }
}

// C[b,d] = sum_m A[b,m]*W[d*Mc+m];  mode 1: C = Mc*acc - wvrow[d]
// grid (4, 32), block 256
__global__ void k_gemm_t(const float* __restrict__ A, const float* __restrict__ W,
                         float* __restrict__ C, int mode, const float* __restrict__ wvrow) {
    __shared__ float Als[Mc];
    int b = blockIdx.y;
    for (int i = threadIdx.x; i < Mc; i += 256) Als[i] = A[(size_t)b * Mc + i];
    __syncthreads();
    int d = blockIdx.x * 256 + threadIdx.x;
    const float4* Wr = (const float4*)(W + (size_t)d * Mc);
    const float4* Ar = (const float4*)Als;
    float acc = 0.f;
#pragma unroll 8
    for (int m4 = 0; m4 < Mc / 4; ++m4) {
        float4 wv = Wr[m4]; float4 av = Ar[m4];
        acc += wv.x * av.x + wv.y * av.y + wv.z * av.z + wv.w * av.w;
    }
    if (mode == 0) C[(size_t)b * Dc + d] = acc;
    else           C[(size_t)b * Dc + d] = (float)Mc * acc - wvrow[d];
}

// LayerNorm + SiLU forward. grid Bc, block 256
__global__ void k_ln_silu(const float* __restrict__ z, const float* __restrict__ g,
                          const float* __restrict__ be, float* __restrict__ h) {
    __shared__ float sm[4];
    int b = blockIdx.x;
    const float* zr = z + (size_t)b * Mc;
    float zv[4];
    float s = 0.f, sq = 0.f;
    for (int j = 0; j < 4; ++j) {
        zv[j] = zr[threadIdx.x + 256 * j];
        s += zv[j]; sq += zv[j] * zv[j];
    }
    s = block_reduce_sum(s, sm);
    sq = block_reduce_sum(sq, sm);
    float mean = s / Mc;
    float var = sq / Mc - mean * mean;
    float rstd = rsqrtf(var + LNEPS);
    for (int j = 0; j < 4; ++j) {
        int m = threadIdx.x + 256 * j;
        float xh = (zv[j] - mean) * rstd;
        float y = fmaf(xh, g[m], be[m]);
        float sg = 1.f / (1.f + __expf(-y));
        h[(size_t)b * Mc + m] = y * sg;
    }
}

// backward of SiLU(LN(z)): dz from upstream gh. grid Bc, block 256
__global__ void k_ln_silu_bwd(const float* __restrict__ gh, const float* __restrict__ z,
                              const float* __restrict__ g, const float* __restrict__ be,
                              float* __restrict__ dz) {
    __shared__ float sm[4];
    int b = blockIdx.x;
    const float* zr = z + (size_t)b * Mc;
    const float* gr = gh + (size_t)b * Mc;
    float zv[4], gv[4];
    float s = 0.f, sq = 0.f;
    for (int j = 0; j < 4; ++j) {
        int m = threadIdx.x + 256 * j;
        zv[j] = zr[m]; gv[j] = gr[m];
        s += zv[j]; sq += zv[j] * zv[j];
    }
    s = block_reduce_sum(s, sm);
    sq = block_reduce_sum(sq, sm);
    float mean = s / Mc;
    float var = sq / Mc - mean * mean;
    float rstd = rsqrtf(var + LNEPS);
    float a[4], xh[4];
    float sa = 0.f, sax = 0.f;
    for (int j = 0; j < 4; ++j) {
        int m = threadIdx.x + 256 * j;
        xh[j] = (zv[j] - mean) * rstd;
        float y = fmaf(xh[j], g[m], be[m]);
        float sg = 1.f / (1.f + __expf(-y));
        float dsilu = sg * (1.f + y * (1.f - sg));
        float dy = gv[j] * dsilu;
        a[j] = dy * g[m];
        sa += a[j]; sax += a[j] * xh[j];
    }
    sa = block_reduce_sum(sa, sm);
    sax = block_reduce_sum(sax, sm);
    float ma = sa / Mc, mx = sax / Mc;
    for (int j = 0; j < 4; ++j) {
        int m = threadIdx.x + 256 * j;
        dz[(size_t)b * Mc + m] = rstd * (a[j] - ma - xh[j] * mx);
    }
}

// cb[b] = Mc * dot(bk, mo_b) - bvsum. grid Bc, block 256
__global__ void k_cb(const float* __restrict__ bk, const float* __restrict__ mo,
                     const float* __restrict__ bvsum, float* __restrict__ cb) {
    __shared__ float sm[4];
    int b = blockIdx.x;
    float v = 0.f;
    for (int m = threadIdx.x; m < Mc; m += 256) v += bk[m] * mo[(size_t)b * Mc + m];
    v = block_reduce_sum(v, sm);
    if (threadIdx.x == 0) cb[b] = (float)Mc * v - *bvsum;
}

// The one pass over X: r[b,s] = X.w_b + c_b ; t += X*r ; p += X ; rs += r
// grid (NCH, Bc), block 256 (4 waves, 16 rows each)
__global__ void k_bigpass(const float* __restrict__ X, const float* __restrict__ w,
                          const float* __restrict__ cb,
                          float* __restrict__ t_part, float* __restrict__ p_part,
                          float* __restrict__ rs_part) {
    __shared__ float red[4][1024];
    __shared__ float rsum_s[4];
    int b = blockIdx.y, ch = blockIdx.x;
    int wv = threadIdx.x >> 6, lane = threadIdx.x & 63;
    float wreg[16], tacc[16], pacc[16];
#pragma unroll
    for (int k = 0; k < 16; ++k) {
        wreg[k] = w[(size_t)b * Dc + lane + 64 * k];
        tacc[k] = 0.f; pacc[k] = 0.f;
    }
    float cbv = cb[b];
    float rloc = 0.f;
    int s0 = ch * 64 + wv * 16;
    for (int i = 0; i < 16; ++i) {
        const float* xr = X + ((size_t)b * Sc + s0 + i) * Dc;
        float x[16];
        float p = 0.f;
#pragma unroll
        for (int k = 0; k < 16; ++k) { x[k] = xr[lane + 64 * k]; p = fmaf(x[k], wreg[k], p); }
        for (int o = 32; o; o >>= 1) p += __shfl_xor(p, o);
        float r = p + cbv;
        rloc += r;
#pragma unroll
        for (int k = 0; k < 16; ++k) { tacc[k] = fmaf(x[k], r, tacc[k]); pacc[k] += x[k]; }
    }
#pragma unroll
    for (int k = 0; k < 16; ++k) red[wv][lane + 64 * k] = tacc[k];
    if (lane == 0) rsum_s[wv] = rloc;
    __syncthreads();
    size_t pb = ((size_t)b * NCH + ch) * Dc;
    for (int j = 0; j < 4; ++j) {
        int d = threadIdx.x + 256 * j;
        t_part[pb + d] = red[0][d] + red[1][d] + red[2][d] + red[3][d];
    }
    if (threadIdx.x == 0) rs_part[b * NCH + ch] = rsum_s[0] + rsum_s[1] + rsum_s[2] + rsum_s[3];
    __syncthreads();
#pragma unroll
    for (int k = 0; k < 16; ++k) red[wv][lane + 64 * k] = pacc[k];
    __syncthreads();
    for (int j = 0; j < 4; ++j) {
        int d = threadIdx.x + 256 * j;
        p_part[pb + d] = red[0][d] + red[1][d] + red[2][d] + red[3][d];
    }
}

// grid 128, block 256
__global__ void k_part_reduce(const float* __restrict__ t_part, const float* __restrict__ p_part,
                              float* __restrict__ t, float* __restrict__ pooled) {
    int idx = blockIdx.x * 256 + threadIdx.x;
    int b = idx >> 10, d = idx & 1023;
    float st = 0.f, sp = 0.f;
    size_t base = (size_t)b * NCH * Dc + d;
    for (int ch = 0; ch < NCH; ++ch) { st += t_part[base + (size_t)ch * Dc]; sp += p_part[base + (size_t)ch * Dc]; }
    t[idx] = st;
    pooled[idx] = sp * (1.f / Sc);
}

__global__ void k_rs_reduce(const float* __restrict__ rs_part, float* __restrict__ rs) {
    int b = threadIdx.x;
    if (b < Bc) {
        float s = 0.f;
        for (int ch = 0; ch < NCH; ++ch) s += rs_part[b * NCH + ch];
        rs[b] = s;
    }
}

// gi = concat(pooled, memory_state). grid 256, block 256
__global__ void k_build_gi(const float* __restrict__ pooled, const float* __restrict__ mem,
                           float* __restrict__ gi) {
    int idx = blockIdx.x * 256 + threadIdx.x;
    int b = idx >> 11, c = idx & 2047;
    gi[idx] = (c < Dc) ? pooled[b * Dc + c] : mem[b * Mc + (c - Dc)];
}

// grid 128, block 256
__global__ void k_update(const float* __restrict__ zgf, const float* __restrict__ zgu,
                         const float* __restrict__ mem, const float* __restrict__ mom,
                         const float* __restrict__ sur,
                         const float* __restrict__ eta, const float* __restrict__ theta,
                         float* __restrict__ newmem, float* __restrict__ out_nm) {
    int idx = blockIdx.x * 256 + threadIdx.x;
    float f = 1.f / (1.f + __expf(-zgf[idx]));
    float u = 1.f / (1.f + __expf(-zgu[idx]));
    float nm = eta[0] * mom[idx] + theta[0] * sur[idx];
    float v = (1.f - f) * mem[idx] + u * nm;
    newmem[idx] = v; out_nm[idx] = v;
}

extern "C" void kernel_launch(void* const* d_in, const int* in_sizes, int n_in,
                              void* d_out, int out_size, void* d_ws, size_t ws_size,
                              hipStream_t stream) {
    const float* X    = (const float*)d_in[0];
    const float* mem  = (const float*)d_in[1];
    const float* mom  = (const float*)d_in[2];
    const float* Wk   = (const float*)d_in[3];
    const float* bk   = (const float*)d_in[4];
    const float* Wv   = (const float*)d_in[5];
    const float* bv   = (const float*)d_in[6];
    const float* memW = (const float*)d_in[7];
    const float* memb = (const float*)d_in[8];
    const float* lng  = (const float*)d_in[9];
    const float* lnb  = (const float*)d_in[10];
    const float* Wf   = (const float*)d_in[11];
    const float* bf   = (const float*)d_in[12];
    const float* Wu   = (const float*)d_in[15];
    const float* bu   = (const float*)d_in[16];
    const float* eta  = (const float*)d_in[17];
    const float* theta= (const float*)d_in[18];
    float* out = (float*)d_out;

    const size_t BM = (size_t)Bc * Mc;
    float* ws = (float*)d_ws;
    float* zf0   = ws + 0 * BM;
    float* zf1   = ws + 1 * BM;
    float* h1    = ws + 2 * BM;
    float* mo    = ws + 3 * BM;
    float* gmo   = ws + 4 * BM;
    float* dz    = ws + 5 * BM;
    float* gh1   = ws + 6 * BM;
    float* sur   = ws + 7 * BM;
    float* zgf   = ws + 8 * BM;
    float* zgu   = ws + 9 * BM;
    float* nmem  = ws + 10 * BM;
    float* zp    = ws + 11 * BM;
    float* hp    = ws + 12 * BM;
    float* gi    = ws + 13 * BM;          // 2*BM
    float* wbuf  = ws + 15 * BM;
    float* tbuf  = ws + 16 * BM;
    float* pooled= ws + 17 * BM;
    float* wv_row= ws + 18 * BM;          // Dc
    float* bvsum = wv_row + Dc;           // 1
    float* cbv   = bvsum + 1;             // Bc
    float* rsv   = cbv + Bc;              // Bc
    float* rs_part = rsv + Bc;            // Bc*NCH
    float* t_part  = ws + 19 * BM;        // 32*BM
    float* p_part  = t_part + 32 * BM;    // 32*BM

    const float SC = 1.f / ((float)Bc * (float)Sc * (float)Mc);
    dim3 gnt(16, 4), gt(4, Bc);

    // wv_row, bvsum
    k_prep<<<Dc + 1, 256, 0, stream>>>(Wv, bv, wv_row, bvsum);
    // mo = f(memory_state), keep pre-LN z's
    k_gemm_nt<1024><<<gnt, 256, 0, stream>>>(mem, memW, memb, zf0, 0, nullptr, 0.f);
    k_ln_silu<<<Bc, 256, 0, stream>>>(zf0, lng, lnb, h1);
    k_gemm_nt<1024><<<gnt, 256, 0, stream>>>(h1, memW + (size_t)Mc * Mc, memb + Mc, zf1, 0, nullptr, 0.f);
    k_ln_silu<<<Bc, 256, 0, stream>>>(zf1, lng + Mc, lnb + Mc, mo);
    // w[b,d] = Mc*(Wk mo)_d - wv_row[d]; c_b
    k_gemm_t<<<gt, 256, 0, stream>>>(mo, Wk, wbuf, 1, wv_row);
    k_cb<<<Bc, 256, 0, stream>>>(bk, mo, bvsum, cbv);
    // single pass over X
    k_bigpass<<<dim3(NCH, Bc), 256, 0, stream>>>(X, wbuf, cbv, t_part, p_part, rs_part);
    k_part_reduce<<<128, 256, 0, stream>>>(t_part, p_part, tbuf, pooled);
    k_rs_reduce<<<1, 64, 0, stream>>>(rs_part, rsv);
    // g_mo = SC*(t@Wk + bk*rs)
    k_gemm_nt<1024><<<gnt, 256, 0, stream>>>(tbuf, Wk, bk, gmo, 1, rsv, SC);
    // backprop through f
    k_ln_silu_bwd<<<Bc, 256, 0, stream>>>(gmo, zf1, lng + Mc, lnb + Mc, dz);
    k_gemm_t<<<gt, 256, 0, stream>>>(dz, memW + (size_t)Mc * Mc, gh1, 0, nullptr);
    k_ln_silu_bwd<<<Bc, 256, 0, stream>>>(gh1, zf0, lng, lnb, dz);
    k_gemm_t<<<gt, 256, 0, stream>>>(dz, memW, sur, 0, nullptr);
    // gates
    k_build_gi<<<256, 256, 0, stream>>>(pooled, mem, gi);
    k_gemm_nt<2048><<<gnt, 256, 0, stream>>>(gi, Wf, bf, zgf, 0, nullptr, 0.f);
    k_gemm_nt<2048><<<gnt, 256, 0, stream>>>(gi, Wu, bu, zgu, 0, nullptr, 0.f);
    // memory update (writes new_memory to out[BM:2BM])
    k_update<<<128, 256, 0, stream>>>(zgf, zgu, mem, mom, sur, eta, theta, nmem, out + BM);
    // processed = f(new_memory) -> out[0:BM]
    k_gemm_nt<1024><<<gnt, 256, 0, stream>>>(nmem, memW, memb, zp, 0, nullptr, 0.f);
    k_ln_silu<<<Bc, 256, 0, stream>>>(zp, lng, lnb, hp);
    k_gemm_nt<1024><<<gnt, 256, 0, stream>>>(hp, memW + (size_t)Mc * Mc, memb + Mc, zf0, 0, nullptr, 0.f);
    k_ln_silu<<<Bc, 256, 0, stream>>>(zf0, lng + Mc, lnb + Mc, out);
}

// Round 2
// 245.250 us; speedup vs baseline: 2.7258x; 2.7258x over previous
//
#include <hip/hip_runtime.h>
#include <math.h>

#define Bc 32
#define Sc 2048
#define Dc 1024
#define Mc 1024
#define NCH 32
#define LNEPS 1e-5f

__device__ __forceinline__ float block_reduce_sum(float v, float* sm) {
    for (int o = 32; o; o >>= 1) v += __shfl_xor(v, o);
    int wid = threadIdx.x >> 6;
    if ((threadIdx.x & 63) == 0) sm[wid] = v;
    __syncthreads();
    float r = sm[0] + sm[1] + sm[2] + sm[3];
    __syncthreads();
    return r;
}

// wv_row[d] = sum_m Wv[d,m]; block Dc handles bvsum = sum(bv)
__global__ void k_prep(const float* __restrict__ Wv, const float* __restrict__ bv,
                       float* __restrict__ wv_row, float* __restrict__ bvsum) {
    __shared__ float sm[4];
    int d = blockIdx.x;
    const float* src = (d < Dc) ? (Wv + (size_t)d * Mc) : bv;
    float v = 0.f;
    for (int m = threadIdx.x; m < Mc; m += 256) v += src[m];
    v = block_reduce_sum(v, sm);
    if (threadIdx.x == 0) { if (d < Dc) wv_row[d] = v; else *bvsum = v; }
}

// Split-K GEMM partial: Pp[ks][b][n] = sum_{k in chunk ks} A[b,k]*W[k*1024+n]
// grid (16 n-tiles, 4 b-tiles, K/256), block 256
__global__ void k_gemm_nt_splitk(const float* __restrict__ A, const float* __restrict__ W,
                                 int K, float* __restrict__ Pp) {
    __shared__ float Als[8 * 256];
    int ks = blockIdx.z, k0 = ks * 256;
    int b0 = blockIdx.y * 8, n0 = blockIdx.x * 64;
    for (int i = threadIdx.x; i < 2048; i += 256) {
        int r = i >> 8, c = i & 255;
        Als[i] = A[(size_t)(b0 + r) * K + k0 + c];
    }
    __syncthreads();
    int n = n0 + (threadIdx.x & 63), bl = threadIdx.x >> 6;
    const float* a0 = Als + bl * 256;
    const float* a1 = Als + (bl + 4) * 256;
    const float* Wp = W + (size_t)k0 * 1024 + n;
    float acc0 = 0.f, acc1 = 0.f;
#pragma unroll 8
    for (int k = 0; k < 256; ++k) {
        float wv = Wp[(size_t)k * 1024];
        acc0 = fmaf(a0[k], wv, acc0);
        acc1 = fmaf(a1[k], wv, acc1);
    }
    size_t base = (size_t)ks * Bc * 1024 + n;
    Pp[base + (size_t)(b0 + bl) * 1024] = acc0;
    Pp[base + (size_t)(b0 + bl + 4) * 1024] = acc1;
}

// merged launch: z<4: tbuf@Wk (K=1024) -> Pg ; z in [4,12): gi@Wf (K=2048) -> Pf ; z in [12,20): gi@Wu -> Pu
__global__ void k_gemm_gates(const float* __restrict__ tbuf, const float* __restrict__ gi,
                             const float* __restrict__ Wk, const float* __restrict__ Wf,
                             const float* __restrict__ Wu,
                             float* __restrict__ Pg, float* __restrict__ Pf, float* __restrict__ Pu) {
    __shared__ float Als[8 * 256];
    int z = blockIdx.z;
    const float *A, *W; float* P; int K, ks;
    if (z < 4)       { A = tbuf; W = Wk; P = Pg; K = 1024; ks = z; }
    else if (z < 12) { A = gi;   W = Wf; P = Pf; K = 2048; ks = z - 4; }
    else             { A = gi;   W = Wu; P = Pu; K = 2048; ks = z - 12; }
    int k0 = ks * 256;
    int b0 = blockIdx.y * 8, n0 = blockIdx.x * 64;
    for (int i = threadIdx.x; i < 2048; i += 256) {
        int r = i >> 8, c = i & 255;
        Als[i] = A[(size_t)(b0 + r) * K + k0 + c];
    }
    __syncthreads();
    int n = n0 + (threadIdx.x & 63), bl = threadIdx.x >> 6;
    const float* a0 = Als + bl * 256;
    const float* a1 = Als + (bl + 4) * 256;
    const float* Wp = W + (size_t)k0 * 1024 + n;
    float acc0 = 0.f, acc1 = 0.f;
#pragma unroll 8
    for (int k = 0; k < 256; ++k) {
        float wv = Wp[(size_t)k * 1024];
        acc0 = fmaf(a0[k], wv, acc0);
        acc1 = fmaf(a1[k], wv, acc1);
    }
    size_t base = (size_t)ks * Bc * 1024 + n;
    P[base + (size_t)(b0 + bl) * 1024] = acc0;
    P[base + (size_t)(b0 + bl + 4) * 1024] = acc1;
}

// Split gemm_t partial: Pp[mc][b][d] = sum_{m in chunk mc} A[b,m]*W[d*1024+m]
// grid (4 d-chunks, 32 b, 4 m-chunks), block 256
__global__ void k_gemm_t_split(const float* __restrict__ A, const float* __restrict__ W,
                               float* __restrict__ Pp) {
    __shared__ float Als[256];
    int b = blockIdx.y, mc = blockIdx.z, m0 = mc * 256;
    Als[threadIdx.x] = A[(size_t)b * 1024 + m0 + threadIdx.x];
    __syncthreads();
    int d = blockIdx.x * 256 + threadIdx.x;
    const float4* Wr = (const float4*)(W + (size_t)d * 1024 + m0);
    const float4* Ar = (const float4*)Als;
    float acc = 0.f;
#pragma unroll 8
    for (int i = 0; i < 64; ++i) {
        float4 w4 = Wr[i], a4 = Ar[i];
        acc += w4.x * a4.x + w4.y * a4.y + w4.z * a4.z + w4.w * a4.w;
    }
    Pp[((size_t)mc * Bc + b) * 1024 + d] = acc;
}

// sum KS partials + bias -> z (stored if z_out) -> LayerNorm -> SiLU -> h
// optional: cb[b] = Mc*dot(bk,h) - bvsum. grid Bc, block 256
__global__ void k_reduce_ln_silu(const float* __restrict__ Pp, int KS,
                                 const float* __restrict__ bias,
                                 const float* __restrict__ g, const float* __restrict__ be,
                                 float* __restrict__ z_out, float* __restrict__ h_out,
                                 const float* __restrict__ bk, const float* __restrict__ bvsum,
                                 float* __restrict__ cb_out) {
    __shared__ float sm[4];
    int b = blockIdx.x;
    float zv[4];
    float s = 0.f, sq = 0.f;
    for (int j = 0; j < 4; ++j) {
        int m = threadIdx.x + 256 * j;
        float acc = bias[m];
        for (int ks = 0; ks < KS; ++ks) acc += Pp[((size_t)ks * Bc + b) * 1024 + m];
        zv[j] = acc; s += acc; sq += acc * acc;
        if (z_out) z_out[(size_t)b * 1024 + m] = acc;
    }
    s = block_reduce_sum(s, sm);
    sq = block_reduce_sum(sq, sm);
    float mean = s / Mc;
    float var = sq / Mc - mean * mean;
    float rstd = rsqrtf(var + LNEPS);
    float cloc = 0.f;
    for (int j = 0; j < 4; ++j) {
        int m = threadIdx.x + 256 * j;
        float xh = (zv[j] - mean) * rstd;
        float y = fmaf(xh, g[m], be[m]);
        float sg = 1.f / (1.f + __expf(-y));
        float h = y * sg;
        h_out[(size_t)b * 1024 + m] = h;
        if (cb_out) cloc += bk[m] * h;
    }
    if (cb_out) {
        cloc = block_reduce_sum(cloc, sm);
        if (threadIdx.x == 0) cb_out[b] = (float)Mc * cloc - *bvsum;
    }
}

// sum KS partials (mode1: gh = scale*(acc + bk[n]*rs[b])) then backward of SiLU(LN(z)).
// grid Bc, block 256
__global__ void k_reduce_lnbwd(const float* __restrict__ Pp, int KS, int mode,
                               const float* __restrict__ bk, const float* __restrict__ rs, float scale,
                               const float* __restrict__ z, const float* __restrict__ g,
                               const float* __restrict__ be, float* __restrict__ dz) {
    __shared__ float sm[4];
    int b = blockIdx.x;
    const float* zr = z + (size_t)b * Mc;
    float zv[4], gv[4];
    float s = 0.f, sq = 0.f;
    for (int j = 0; j < 4; ++j) {
        int m = threadIdx.x + 256 * j;
        float acc = 0.f;
        for (int ks = 0; ks < KS; ++ks) acc += Pp[((size_t)ks * Bc + b) * 1024 + m];
        if (mode) acc = scale * (acc + bk[m] * rs[b]);
        gv[j] = acc;
        zv[j] = zr[m];
        s += zv[j]; sq += zv[j] * zv[j];
    }
    s = block_reduce_sum(s, sm);
    sq = block_reduce_sum(sq, sm);
    float mean = s / Mc;
    float var = sq / Mc - mean * mean;
    float rstd = rsqrtf(var + LNEPS);
    float a[4], xh[4];
    float sa = 0.f, sax = 0.f;
    for (int j = 0; j < 4; ++j) {
        int m = threadIdx.x + 256 * j;
        xh[j] = (zv[j] - mean) * rstd;
        float y = fmaf(xh[j], g[m], be[m]);
        float sg = 1.f / (1.f + __expf(-y));
        float dsilu = sg * (1.f + y * (1.f - sg));
        float dy = gv[j] * dsilu;
        a[j] = dy * g[m];
        sa += a[j]; sax += a[j] * xh[j];
    }
    sa = block_reduce_sum(sa, sm);
    sax = block_reduce_sum(sax, sm);
    float ma = sa / Mc, mx = sax / Mc;
    for (int j = 0; j < 4; ++j) {
        int m = threadIdx.x + 256 * j;
        dz[(size_t)b * Mc + m] = rstd * (a[j] - ma - xh[j] * mx);
    }
}

// The one pass over X: r[b,s] = X.w_b + c_b ; t += X*r ; p += X ; rs += r
// w_b summed from 4 gemm_t partials: w = Mc*sum(wpart) - wv_row
// grid (NCH, Bc), block 256 (4 waves, 16 rows each), float4 loads
__global__ void k_bigpass(const float* __restrict__ X, const float* __restrict__ wpart,
                          const float* __restrict__ wv_row, const float* __restrict__ cb,
                          float* __restrict__ t_part, float* __restrict__ p_part,
                          float* __restrict__ rs_part) {
    __shared__ float red[4][1024];
    __shared__ float rsum_s[4];
    int b = blockIdx.y, ch = blockIdx.x;
    int wv = threadIdx.x >> 6, lane = threadIdx.x & 63;
    float4 wreg[4], tacc[4], pacc[4];
    const float4* wp4 = (const float4*)wpart;
    const float4* wr4 = (const float4*)wv_row;
#pragma unroll
    for (int j = 0; j < 4; ++j) {
        int d4 = lane + 64 * j;
        float4 s0 = wp4[((size_t)(0 * Bc + b)) * 256 + d4];
        float4 s1 = wp4[((size_t)(1 * Bc + b)) * 256 + d4];
        float4 s2 = wp4[((size_t)(2 * Bc + b)) * 256 + d4];
        float4 s3 = wp4[((size_t)(3 * Bc + b)) * 256 + d4];
        float4 wr = wr4[d4];
        wreg[j].x = 1024.f * (s0.x + s1.x + s2.x + s3.x) - wr.x;
        wreg[j].y = 1024.f * (s0.y + s1.y + s2.y + s3.y) - wr.y;
        wreg[j].z = 1024.f * (s0.z + s1.z + s2.z + s3.z) - wr.z;
        wreg[j].w = 1024.f * (s0.w + s1.w + s2.w + s3.w) - wr.w;
        tacc[j] = make_float4(0.f, 0.f, 0.f, 0.f);
        pacc[j] = make_float4(0.f, 0.f, 0.f, 0.f);
    }
    float cbv = cb[b];
    float rloc = 0.f;
    int s0r = ch * 64 + wv * 16;
    for (int i = 0; i < 16; ++i) {
        const float4* xr = (const float4*)(X + ((size_t)b * Sc + s0r + i) * Dc);
        float4 x[4];
        float p = 0.f;
#pragma unroll
        for (int j = 0; j < 4; ++j) {
            x[j] = xr[lane + 64 * j];
            p += x[j].x * wreg[j].x + x[j].y * wreg[j].y + x[j].z * wreg[j].z + x[j].w * wreg[j].w;
        }
        for (int o = 32; o; o >>= 1) p += __shfl_xor(p, o);
        float r = p + cbv;
        rloc += r;
#pragma unroll
        for (int j = 0; j < 4; ++j) {
            tacc[j].x = fmaf(x[j].x, r, tacc[j].x);
            tacc[j].y = fmaf(x[j].y, r, tacc[j].y);
            tacc[j].z = fmaf(x[j].z, r, tacc[j].z);
            tacc[j].w = fmaf(x[j].w, r, tacc[j].w);
            pacc[j].x += x[j].x; pacc[j].y += x[j].y; pacc[j].z += x[j].z; pacc[j].w += x[j].w;
        }
    }
    float4* redv = (float4*)red[wv];
#pragma unroll
    for (int j = 0; j < 4; ++j) redv[lane + 64 * j] = tacc[j];
    if (lane == 0) rsum_s[wv] = rloc;
    __syncthreads();
    size_t pb = ((size_t)b * NCH + ch) * Dc;
    for (int j = 0; j < 4; ++j) {
        int d = threadIdx.x + 256 * j;
        t_part[pb + d] = red[0][d] + red[1][d] + red[2][d] + red[3][d];
    }
    if (threadIdx.x == 0) rs_part[b * NCH + ch] = rsum_s[0] + rsum_s[1] + rsum_s[2] + rsum_s[3];
    __syncthreads();
#pragma unroll
    for (int j = 0; j < 4; ++j) redv[lane + 64 * j] = pacc[j];
    __syncthreads();
    for (int j = 0; j < 4; ++j) {
        int d = threadIdx.x + 256 * j;
        p_part[pb + d] = red[0][d] + red[1][d] + red[2][d] + red[3][d];
    }
}

// chunk reduce + build gi(concat pooled,mem) + rs reduce. grid 128, block 256
__global__ void k_part_reduce2(const float* __restrict__ t_part, const float* __restrict__ p_part,
                               const float* __restrict__ rs_part, const float* __restrict__ mem,
                               float* __restrict__ tbuf, float* __restrict__ gi,
                               float* __restrict__ rsv) {
    int idx = blockIdx.x * 256 + threadIdx.x;
    int b = idx >> 10, d = idx & 1023;
    float st = 0.f, sp = 0.f;
    size_t base = (size_t)b * NCH * Dc + d;
    for (int ch = 0; ch < NCH; ++ch) {
        st += t_part[base + (size_t)ch * Dc];
        sp += p_part[base + (size_t)ch * Dc];
    }
    tbuf[idx] = st;
    gi[(size_t)b * 2048 + d] = sp * (1.f / Sc);
    gi[(size_t)b * 2048 + 1024 + d] = mem[idx];
    if (blockIdx.x == 0 && threadIdx.x < Bc) {
        float s = 0.f;
        for (int ch = 0; ch < NCH; ++ch) s += rs_part[threadIdx.x * NCH + ch];
        rsv[threadIdx.x] = s;
    }
}

// gate partial sums + sigmoid + sur partial sum + memory update. grid 128, block 256
__global__ void k_update2(const float* __restrict__ Pf, const float* __restrict__ Pu,
                          const float* __restrict__ surpart,
                          const float* __restrict__ bf, const float* __restrict__ bu,
                          const float* __restrict__ mem, const float* __restrict__ mom,
                          const float* __restrict__ eta, const float* __restrict__ theta,
                          float* __restrict__ nmem, float* __restrict__ out_nm) {
    int idx = blockIdx.x * 256 + threadIdx.x;
    int b = idx >> 10, n = idx & 1023;
    float zf = bf[n], zu = bu[n];
    for (int ks = 0; ks < 8; ++ks) {
        zf += Pf[((size_t)ks * Bc + b) * 1024 + n];
        zu += Pu[((size_t)ks * Bc + b) * 1024 + n];
    }
    float sv = 0.f;
    for (int mc = 0; mc < 4; ++mc) sv += surpart[((size_t)mc * Bc + b) * 1024 + n];
    float f = 1.f / (1.f + __expf(-zf));
    float u = 1.f / (1.f + __expf(-zu));
    float nm = eta[0] * mom[idx] + theta[0] * sv;
    float v = (1.f - f) * mem[idx] + u * nm;
    nmem[idx] = v; out_nm[idx] = v;
}

extern "C" void kernel_launch(void* const* d_in, const int* in_sizes, int n_in,
                              void* d_out, int out_size, void* d_ws, size_t ws_size,
                              hipStream_t stream) {
    const float* X    = (const float*)d_in[0];
    const float* mem  = (const float*)d_in[1];
    const float* mom  = (const float*)d_in[2];
    const float* Wk   = (const float*)d_in[3];
    const float* bk   = (const float*)d_in[4];
    const float* Wv   = (const float*)d_in[5];
    const float* bv   = (const float*)d_in[6];
    const float* memW = (const float*)d_in[7];
    const float* memb = (const float*)d_in[8];
    const float* lng  = (const float*)d_in[9];
    const float* lnb  = (const float*)d_in[10];
    const float* Wf   = (const float*)d_in[11];
    const float* bf   = (const float*)d_in[12];
    const float* Wu   = (const float*)d_in[15];
    const float* bu   = (const float*)d_in[16];
    const float* eta  = (const float*)d_in[17];
    const float* theta= (const float*)d_in[18];
    float* out = (float*)d_out;

    const size_t BM = (size_t)Bc * Mc;
    float* ws = (float*)d_ws;
    float* zf0    = ws + 0 * BM;
    float* zf1    = ws + 1 * BM;
    float* h1     = ws + 2 * BM;
    float* mo     = ws + 3 * BM;
    float* dz     = ws + 4 * BM;
    float* dz2    = ws + 5 * BM;
    float* hp     = ws + 6 * BM;
    float* gi     = ws + 7 * BM;   // 2*BM
    float* tbuf   = ws + 9 * BM;
    float* nmem   = ws + 10 * BM;
    float* Pmlp   = ws + 11 * BM;  // 4*BM, reused by all mlp gemms
    float* Pg     = ws + 15 * BM;  // 4*BM
    float* Pf     = ws + 19 * BM;  // 8*BM
    float* Pu     = ws + 27 * BM;  // 8*BM
    float* wpart  = ws + 35 * BM;  // 4*BM
    float* ghpart = ws + 39 * BM;  // 4*BM
    float* surpart= ws + 43 * BM;  // 4*BM
    float* wv_row = ws + 47 * BM;  // Dc
    float* bvsum  = wv_row + Dc;   // 1
    float* cbv    = bvsum + 1;     // Bc
    float* rsv    = cbv + Bc;      // Bc
    float* rs_part= rsv + Bc;      // Bc*NCH
    float* t_part = ws + 48 * BM;  // 32*BM
    float* p_part = ws + 80 * BM;  // 32*BM

    const float SC = 1.f / ((float)Bc * (float)Sc * (float)Mc);
    const float* W1 = memW + (size_t)Mc * Mc;
    dim3 gsk(16, 4, 4), ggt(4, Bc, 4);

    // wv_row, bvsum (independent)
    k_prep<<<Dc + 1, 256, 0, stream>>>(Wv, bv, wv_row, bvsum);
    // mo = f(memory_state); keep pre-LN z's; fuse cb into second LN
    k_gemm_nt_splitk<<<gsk, 256, 0, stream>>>(mem, memW, 1024, Pmlp);
    k_reduce_ln_silu<<<Bc, 256, 0, stream>>>(Pmlp, 4, memb, lng, lnb, zf0, h1, nullptr, nullptr, nullptr);
    k_gemm_nt_splitk<<<gsk, 256, 0, stream>>>(h1, W1, 1024, Pmlp);
    k_reduce_ln_silu<<<Bc, 256, 0, stream>>>(Pmlp, 4, memb + Mc, lng + Mc, lnb + Mc, zf1, mo, bk, bvsum, cbv);
    // wpart = partials of mo@Wk^T (bigpass folds Mc*sum - wv_row)
    k_gemm_t_split<<<ggt, 256, 0, stream>>>(mo, Wk, wpart);
    // single pass over X
    k_bigpass<<<dim3(NCH, Bc), 256, 0, stream>>>(X, wpart, wv_row, cbv, t_part, p_part, rs_part);
    // chunk reduce + gi build + rs reduce
    k_part_reduce2<<<128, 256, 0, stream>>>(t_part, p_part, rs_part, mem, tbuf, gi, rsv);
    // merged: tbuf@Wk, gi@Wf, gi@Wu
    k_gemm_gates<<<dim3(16, 4, 20), 256, 0, stream>>>(tbuf, gi, Wk, Wf, Wu, Pg, Pf, Pu);
    // backprop through f
    k_reduce_lnbwd<<<Bc, 256, 0, stream>>>(Pg, 4, 1, bk, rsv, SC, zf1, lng + Mc, lnb + Mc, dz);
    k_gemm_t_split<<<ggt, 256, 0, stream>>>(dz, W1, ghpart);
    k_reduce_lnbwd<<<Bc, 256, 0, stream>>>(ghpart, 4, 0, nullptr, nullptr, 0.f, zf0, lng, lnb, dz2);
    k_gemm_t_split<<<ggt, 256, 0, stream>>>(dz2, memW, surpart);
    // gates + update (writes new_memory to out[BM:2BM])
    k_update2<<<128, 256, 0, stream>>>(Pf, Pu, surpart, bf, bu, mem, mom, eta, theta, nmem, out + BM);
    // processed = f(new_memory) -> out[0:BM]
    k_gemm_nt_splitk<<<gsk, 256, 0, stream>>>(nmem, memW, 1024, Pmlp);
    k_reduce_ln_silu<<<Bc, 256, 0, stream>>>(Pmlp, 4, memb, lng, lnb, nullptr, hp, nullptr, nullptr, nullptr);
    k_gemm_nt_splitk<<<gsk, 256, 0, stream>>>(hp, W1, 1024, Pmlp);
    k_reduce_ln_silu<<<Bc, 256, 0, stream>>>(Pmlp, 4, memb + Mc, lng + Mc, lnb + Mc, nullptr, out, nullptr, nullptr, nullptr);
}